// Round 15
// baseline (1981.632 us; speedup 1.0000x reference)
//
#include <hip/hip_runtime.h>

#define T_SEQ 256
#define DMODEL 1024
#define NHEAD 16
#define HSZ 64
#define NLAYER 12
#define VOCAB 50257
#define NPAD 50304
#define FF 4096
#define MROWS 2048
#define NSTRIPS 786

using short8 = __attribute__((ext_vector_type(8))) short;
using f32x4  = __attribute__((ext_vector_type(4))) float;

__device__ __forceinline__ float bf2f(unsigned short u) {
    unsigned int x = ((unsigned int)u) << 16;
    return __builtin_bit_cast(float, x);
}
__device__ __forceinline__ unsigned short f2bf(float f) {
    unsigned int u = __builtin_bit_cast(unsigned int, f);
    unsigned int r = (u + 0x7fffu + ((u >> 16) & 1u)) >> 16;
    return (unsigned short)r;
}
__device__ __forceinline__ void async_copy16(const void* g, void* l) {
    __builtin_amdgcn_global_load_lds(
        (const __attribute__((address_space(1))) unsigned int*)g,
        (__attribute__((address_space(3))) unsigned int*)l, 16, 0, 0);
}

// ---------------------------------------------------------------------------
// Shared LN tail
// ---------------------------------------------------------------------------
__device__ __forceinline__ void ln_tail(
    float4 v, const float* __restrict__ g, const float* __restrict__ b,
    int row, int tid, unsigned short* __restrict__ out)
{
    float s  = v.x + v.y + v.z + v.w;
    float ss = v.x * v.x + v.y * v.y + v.z * v.z + v.w * v.w;
    for (int o = 32; o > 0; o >>= 1) {
        s  += __shfl_down(s, o);
        ss += __shfl_down(ss, o);
    }
    __shared__ float ps[4], pss[4];
    int wave = tid >> 6, lane = tid & 63;
    if (lane == 0) { ps[wave] = s; pss[wave] = ss; }
    __syncthreads();
    float st  = ps[0] + ps[1] + ps[2] + ps[3];
    float sst = pss[0] + pss[1] + pss[2] + pss[3];
    float mu  = st * (1.0f / DMODEL);
    float var = sst * (1.0f / DMODEL) - mu * mu;
    float rstd = rsqrtf(var + 1e-5f);
    float4 gv = ((const float4*)g)[tid];
    float4 bv = ((const float4*)b)[tid];
    ushort4 o4;
    o4.x = f2bf((v.x - mu) * rstd * gv.x + bv.x);
    o4.y = f2bf((v.y - mu) * rstd * gv.y + bv.y);
    o4.z = f2bf((v.z - mu) * rstd * gv.z + bv.z);
    o4.w = f2bf((v.w - mu) * rstd * gv.w + bv.w);
    ((ushort4*)out)[(size_t)row * (DMODEL / 4) + tid] = o4;
}

// ---------------------------------------------------------------------------
// Embedding fused with layer-0 ln1
// ---------------------------------------------------------------------------
__global__ __launch_bounds__(256) void embed_ln_kernel(
    const int* __restrict__ idx, const float* __restrict__ tok,
    const float* __restrict__ pos, const float* __restrict__ g,
    const float* __restrict__ b, float* __restrict__ x,
    unsigned short* __restrict__ h)
{
    int row = blockIdx.x, tid = threadIdx.x;
    int t = row & (T_SEQ - 1);
    int token = idx[row];
    float4 a = ((const float4*)(tok + (size_t)token * DMODEL))[tid];
    float4 p = ((const float4*)(pos + (size_t)t * DMODEL))[tid];
    float4 v;
    v.x = a.x + p.x; v.y = a.y + p.y; v.z = a.z + p.z; v.w = a.w + p.w;
    ((float4*)(x + (size_t)row * DMODEL))[tid] = v;
    ln_tail(v, g, b, row, tid, h);
}

// ---------------------------------------------------------------------------
// Plain LayerNorm (ln2)
// ---------------------------------------------------------------------------
__global__ __launch_bounds__(256) void ln_kernel(
    const float* __restrict__ x, const float* __restrict__ g,
    const float* __restrict__ b, unsigned short* __restrict__ out)
{
    int row = blockIdx.x, tid = threadIdx.x;
    float4 v = ((const float4*)(x + (size_t)row * DMODEL))[tid];
    ln_tail(v, g, b, row, tid, out);
}

// ---------------------------------------------------------------------------
// fc2 partial merge + residual + NEXT layer's ln1 (or lnf), fused
// ---------------------------------------------------------------------------
__global__ __launch_bounds__(256) void fc2_merge_ln_kernel(
    const float* __restrict__ part, const float* __restrict__ bias,
    const float* __restrict__ g, const float* __restrict__ b,
    float* __restrict__ x, unsigned short* __restrict__ h)
{
    int row = blockIdx.x, tid = threadIdx.x;
    size_t o = (size_t)row * (DMODEL / 4) + tid;
    float4 p0 = ((const float4*)part)[o];
    float4 p1 = ((const float4*)part)[o + MROWS * (DMODEL / 4)];
    float4 bv = ((const float4*)bias)[tid];
    float4 v = ((float4*)x)[o];
    v.x += p0.x + p1.x + bv.x;
    v.y += p0.y + p1.y + bv.y;
    v.z += p0.z + p1.z + bv.z;
    v.w += p0.w + p1.w + bv.w;
    ((float4*)x)[o] = v;
    ln_tail(v, g, b, row, tid, h);
}

// ---------------------------------------------------------------------------
// 32x128 weight transpose: in [R,C] f32 -> out [C,R] bf16.
// Block: 128 in-rows x 32 in-cols. Writes 256B contiguous per out-row
// (16 lanes x ushort8). Grid (ceil(C/32) [pad-covered], R/128, layers);
// reads col-guarded (pad cols -> 0).
// ---------------------------------------------------------------------------
__global__ __launch_bounds__(256) void wtranspose128_kernel(
    const float* __restrict__ in, unsigned short* __restrict__ out,
    int R, int C, long in_l, long out_l)
{
    int lyr = blockIdx.z;
    in  += (size_t)lyr * in_l;
    out += (size_t)lyr * out_l;
    __shared__ float tile[128][33];
    int c0 = blockIdx.x * 32, r0 = blockIdx.y * 128;
    int rr = threadIdx.x >> 3;          // 0..31
    int cc4 = (threadIdx.x & 7) * 4;    // 0,4,..28
    #pragma unroll
    for (int i = 0; i < 4; i++) {
        int r = i * 32 + rr;
        int gc = c0 + cc4;
        const float* src = in + (size_t)(r0 + r) * C + gc;
        float4 v;
        if (gc + 3 < C) {
            v = *(const float4*)src;
        } else {
            v.x = (gc     < C) ? src[0] : 0.f;
            v.y = (gc + 1 < C) ? src[1] : 0.f;
            v.z = (gc + 2 < C) ? src[2] : 0.f;
            v.w = (gc + 3 < C) ? src[3] : 0.f;
        }
        tile[r][cc4] = v.x; tile[r][cc4 + 1] = v.y;
        tile[r][cc4 + 2] = v.z; tile[r][cc4 + 3] = v.w;
    }
    __syncthreads();
    int col8 = (threadIdx.x & 15) * 8;  // 0..120
    #pragma unroll
    for (int i = 0; i < 2; i++) {
        int c = (threadIdx.x >> 4) + i * 16;   // 0..31
        unsigned short w[8];
        #pragma unroll
        for (int j = 0; j < 8; j++) w[j] = f2bf(tile[col8 + j][c]);
        *(short8*)(void*)(out + (size_t)(c0 + c) * R + r0 + col8) = *(short8*)(void*)w;
    }
}

// ---------------------------------------------------------------------------
// 64x64 QKV weight pack (HSZ=64 constrains tile)
// ---------------------------------------------------------------------------
__global__ __launch_bounds__(256) void qkvpack64_kernel(
    const float* __restrict__ Wq, const float* __restrict__ Wk,
    const float* __restrict__ Wv, unsigned short* __restrict__ out,
    long w_l, long out_l)
{
    int z = blockIdx.z;
    int lyr = z / 48, r48 = z % 48;
    int seg = r48 >> 4, hh = r48 & 15;
    const float* W = (seg == 0 ? Wq : seg == 1 ? Wk : Wv)
                     + (size_t)lyr * w_l + (size_t)hh * DMODEL * HSZ;
    unsigned short* o = out + (size_t)lyr * out_l
                      + (size_t)(seg * 1024 + hh * 64) * DMODEL;
    __shared__ float tile[64][65];
    int tx = threadIdx.x & 15, ty = threadIdx.x >> 4;
    int d0 = blockIdx.x * 64;
    #pragma unroll
    for (int i = 0; i < 4; i++) {
        int d = ty + i * 16;
        float4 v = *(const float4*)(W + (size_t)(d0 + d) * HSZ + tx * 4);
        tile[d][tx * 4] = v.x; tile[d][tx * 4 + 1] = v.y;
        tile[d][tx * 4 + 2] = v.z; tile[d][tx * 4 + 3] = v.w;
    }
    __syncthreads();
    int db = (threadIdx.x & 7) * 8;
    int sb = threadIdx.x >> 3;
    #pragma unroll
    for (int i = 0; i < 2; i++) {
        int s = sb + i * 32;
        unsigned short w[8];
        #pragma unroll
        for (int j = 0; j < 8; j++) w[j] = f2bf(tile[db + j][s]);
        *(short8*)(void*)(o + (size_t)s * DMODEL + d0 + db) = *(short8*)(void*)w;
    }
}

// ---------------------------------------------------------------------------
// Shared bf16 MFMA GEMM core.
// PIPE=false: single-buffer 2x __syncthreads (R12 baseline).
// PIPE=true : T4 counted-vmcnt pipeline (R14, -79us proven).
// Keep >=2 blocks/CU (R6/R11 trap).
// ---------------------------------------------------------------------------
template<int MF, int WAVES, int WCOLS, bool QKV, bool RELU, bool RES,
         bool CBF16, bool LOSSP, bool PIPE>
__device__ __forceinline__ void gemm_core(
    const unsigned short* __restrict__ A, int lda,
    const unsigned short* __restrict__ Bt, int ldb,
    const float* __restrict__ bias,
    void* __restrict__ Cv, int ldc,
    const float* __restrict__ res, int ldr,
    int N, int K,
    unsigned short* __restrict__ vtout,
    float* __restrict__ pmax, float* __restrict__ psum)
{
    constexpr int BM = MF * 16 * (WAVES / WCOLS);
    constexpr int BN = 64 * WCOLS;
    constexpr int AJ = (BM * 8) / (WAVES * 64);
    constexpr int BJ = (BN * 8) / (WAVES * 64);
    constexpr int NLD = AJ + BJ;
    constexpr int NBUF = PIPE ? 2 : 1;
    __shared__ __align__(16) char As[NBUF][BM * 128];
    __shared__ __align__(16) char Bs[NBUF][BN * 128];
    int tid = threadIdx.x;
    int wave = tid >> 6, lane = tid & 63;
    int wr = wave / WCOLS, wc = wave % WCOLS;
    int m0 = blockIdx.x * BM, n0 = blockIdx.y * BN;

    f32x4 acc[MF][4];
    #pragma unroll
    for (int m = 0; m < MF; m++)
        #pragma unroll
        for (int n = 0; n < 4; n++)
            acc[m][n] = (f32x4){0.f, 0.f, 0.f, 0.f};

    int ksw = (((lane & 7) ^ (lane >> 3)) << 4);
    int KT = K >> 6;

    auto stage = [&](int kt, int bi) {
        int k0 = kt << 6;
        #pragma unroll
        for (int j = 0; j < AJ; j++) {
            int row = (wave * AJ + j) * 8 + (lane >> 3);
            const char* src = (const char*)A + ((size_t)(m0 + row) * lda + k0) * 2 + ksw;
            async_copy16(src, As[bi] + (wave * AJ + j) * 1024);
        }
        #pragma unroll
        for (int j = 0; j < BJ; j++) {
            int nrow = (wave * BJ + j) * 8 + (lane >> 3);
            const char* src = (const char*)Bt + ((size_t)(n0 + nrow) * ldb + k0) * 2 + ksw;
            async_copy16(src, Bs[bi] + (wave * BJ + j) * 1024);
        }
    };
    auto compute = [&](int bi) {
        #pragma unroll
        for (int ks = 0; ks < 2; ks++) {
            int kb = ks * 64 + ((lane >> 4) << 4);
            short8 a[MF], b[4];
            #pragma unroll
            for (int m = 0; m < MF; m++) {
                int r = wr * (MF * 16) + m * 16 + (lane & 15);
                a[m] = *(const short8*)(const void*)(As[bi] + r * 128 + (kb ^ ((r & 7) << 4)));
            }
            #pragma unroll
            for (int n = 0; n < 4; n++) {
                int c = wc * 64 + n * 16 + (lane & 15);
                b[n] = *(const short8*)(const void*)(Bs[bi] + c * 128 + (kb ^ ((c & 7) << 4)));
            }
            #pragma unroll
            for (int m = 0; m < MF; m++)
                #pragma unroll
                for (int n = 0; n < 4; n++)
                    acc[m][n] = __builtin_amdgcn_mfma_f32_16x16x32_bf16(a[m], b[n], acc[m][n], 0, 0, 0);
        }
    };

    if (PIPE) {
        stage(0, 0);
        stage(1, 1);
        for (int kt = 0; kt < KT; kt++) {
            int cur = kt & 1;
            if (kt + 1 < KT) {
                asm volatile("s_waitcnt vmcnt(%0)" :: "n"(NLD) : "memory");
            } else {
                asm volatile("s_waitcnt vmcnt(0)" ::: "memory");
            }
            __builtin_amdgcn_sched_barrier(0);
            __builtin_amdgcn_s_barrier();
            compute(cur);
            __builtin_amdgcn_s_barrier();
            if (kt + 2 < KT) stage(kt + 2, cur);
        }
    } else {
        for (int kt = 0; kt < KT; kt++) {
            __syncthreads();
            stage(kt, 0);
            __syncthreads();
            compute(0);
        }
    }

    #pragma unroll
    for (int m = 0; m < MF; m++) {
        int rowb = m0 + wr * (MF * 16) + m * 16 + ((lane >> 4) << 2);
        float val[4][4];
        #pragma unroll
        for (int n = 0; n < 4; n++) {
            int col = n0 + wc * 64 + n * 16 + (lane & 15);
            bool okc = (col < N);
            float bi = (bias && okc) ? bias[col] : 0.f;
            #pragma unroll
            for (int r2 = 0; r2 < 4; r2++) {
                float v = acc[m][n][r2] + bi;
                if (RELU) v = fmaxf(v, 0.f);
                int row = rowb + r2;
                if (okc) {
                    if (RES) v += res[(size_t)row * ldr + col];
                    if (QKV && col >= 2048) {
                        int hh = (col - 2048) >> 6, sdim = (col - 2048) & 63;
                        int bb = row >> 8, tt = row & 255;
                        vtout[((((size_t)bb * NHEAD + hh) * HSZ + sdim) * T_SEQ) + tt] = f2bf(v);
                    } else if (CBF16) {
                        ((unsigned short*)Cv)[(size_t)row * ldc + col] = f2bf(v);
                    } else {
                        ((float*)Cv)[(size_t)row * ldc + col] = v;
                    }
                }
                if (LOSSP) val[n][r2] = okc ? v : -1e30f;
            }
        }
        if (LOSSP) {
            #pragma unroll
            for (int r2 = 0; r2 < 4; r2++) {
                float M = fmaxf(fmaxf(val[0][r2], val[1][r2]),
                                fmaxf(val[2][r2], val[3][r2]));
                #pragma unroll
                for (int o = 1; o < 16; o <<= 1) M = fmaxf(M, __shfl_xor(M, o));
                float S = 0.f;
                #pragma unroll
                for (int n = 0; n < 4; n++) S += __expf(val[n][r2] - M);
                #pragma unroll
                for (int o = 1; o < 16; o <<= 1) S += __shfl_xor(S, o);
                if ((lane & 15) == 0) {
                    int row = rowb + r2;
                    int strip = blockIdx.y * WCOLS + wc;
                    pmax[(size_t)row * NSTRIPS + strip] = M;
                    psum[(size_t)row * NSTRIPS + strip] = S;
                }
            }
        }
    }
}

__global__ __launch_bounds__(256) void gemm_qkv(
    const unsigned short* __restrict__ A, const unsigned short* __restrict__ Bt,
    unsigned short* __restrict__ C, unsigned short* __restrict__ vtout)
{
    gemm_core<4, 4, 2, true, false, false, true, false, true>(
        A, DMODEL, Bt, DMODEL, nullptr, C, 3072, nullptr, 0, 3072, DMODEL,
        vtout, nullptr, nullptr);
}

__global__ __launch_bounds__(256) void gemm_fc1(
    const unsigned short* __restrict__ A, const unsigned short* __restrict__ Bt,
    const float* __restrict__ bias, unsigned short* __restrict__ C)
{
    gemm_core<4, 4, 2, false, true, false, true, false, true>(
        A, DMODEL, Bt, DMODEL, bias, C, FF, nullptr, 0, FF, DMODEL,
        nullptr, nullptr, nullptr);
}

__global__ __launch_bounds__(256) void gemm_fc2(
    const unsigned short* __restrict__ A, const unsigned short* __restrict__ Bt,
    float* __restrict__ part)
{
    int z = blockIdx.z;
    gemm_core<2, 4, 2, false, false, false, false, false, true>(
        A + z * 2048, FF, Bt + z * 2048, FF, nullptr,
        part + (size_t)z * MROWS * DMODEL, DMODEL, nullptr, 0,
        DMODEL, 2048, nullptr, nullptr, nullptr);
}

// LM head: 8 waves 256x128 + fused loss partials; NOT piped (dbuf = 96KB ->
// 1 block/CU occupancy cliff; R11 evidence).
__global__ __launch_bounds__(512) void gemm_lm(
    const unsigned short* __restrict__ A, const unsigned short* __restrict__ Bt,
    const float* __restrict__ bias, float* __restrict__ C,
    float* __restrict__ pmax, float* __restrict__ psum)
{
    gemm_core<4, 8, 2, false, false, false, false, true, false>(
        A, DMODEL, Bt, DMODEL, bias, C, VOCAB, nullptr, 0, VOCAB, DMODEL,
        nullptr, pmax, psum);
}

// ---------------------------------------------------------------------------
// Fused flash attention (MFMA), all-resident K/V + defer-max (T13, THR=8)
// ---------------------------------------------------------------------------
__global__ __launch_bounds__(256) void attn_fused_kernel(
    const unsigned short* __restrict__ qkv, const unsigned short* __restrict__ vt,
    float* __restrict__ x)
{
    int qt = blockIdx.x, hh = blockIdx.y, b = blockIdx.z;
    int tid = threadIdx.x;
    int wave = tid >> 6, lane = tid & 63;
    int g = lane >> 4, q = lane & 15;

    __shared__ __align__(16) char Kb[4][8192];
    __shared__ __align__(16) char Vb[4][8192];
    __shared__ __align__(16) char Plds[4][2048];

    int qrow = b * T_SEQ + qt * 64 + wave * 16 + q;
    const char* qp = (const char*)qkv + ((size_t)qrow * 3072 + hh * HSZ) * 2;
    short8 qreg[2];
    qreg[0] = *(const short8*)(const void*)(qp + (g << 4));
    qreg[1] = *(const short8*)(const void*)(qp + 64 + (g << 4));

    char* Pw = Plds[wave];

    f32x4 oacc[4];
    #pragma unroll
    for (int f = 0; f < 4; f++) oacc[f] = (f32x4){0.f, 0.f, 0.f, 0.f};
    float m_run = -1e30f, l_run = 0.f;

    int srow = wave * 8 + (lane >> 3);
    int sbyte = ((lane & 7) << 4) ^ ((srow & 7) << 4);

    for (int kt = 0; kt <= qt; kt++) {
        #pragma unroll
        for (int c = 0; c < 2; c++) {
            int row = c * 32 + srow;
            const char* src = (const char*)qkv +
                ((size_t)(b * T_SEQ + kt * 64 + row) * 3072 + 1024 + hh * HSZ) * 2 + sbyte;
            async_copy16(src, Kb[kt] + c * 4096 + wave * 1024);
        }
        #pragma unroll
        for (int c = 0; c < 2; c++) {
            int row = c * 32 + srow;
            const char* src = (const char*)vt +
                (((size_t)(b * NHEAD + hh) * HSZ + row) * T_SEQ + kt * 64) * 2 + sbyte;
            async_copy16(src, Vb[kt] + c * 4096 + wave * 1024);
        }
    }
    __syncthreads();

    for (int kt = 0; kt <= qt; kt++) {
        f32x4 sacc[4];
        #pragma unroll
        for (int f = 0; f < 4; f++) sacc[f] = (f32x4){0.f, 0.f, 0.f, 0.f};
        #pragma unroll
        for (int ks = 0; ks < 2; ks++) {
            int kb = ks * 64 + (g << 4);
            #pragma unroll
            for (int f = 0; f < 4; f++) {
                int u = f * 16 + q;
                short8 kf = *(const short8*)(const void*)(Kb[kt] + u * 128 + (kb ^ ((u & 7) << 4)));
                sacc[f] = __builtin_amdgcn_mfma_f32_16x16x32_bf16(kf, qreg[ks], sacc[f], 0, 0, 0);
            }
        }
        float sv[4][4];
        #pragma unroll
        for (int f = 0; f < 4; f++)
            #pragma unroll
            for (int r = 0; r < 4; r++) {
                float v = sacc[f][r] * 0.125f;
                if (kt == qt) {
                    int u_loc = f * 16 + g * 4 + r;
                    if (u_loc > wave * 16 + q) v = -1e30f;
                }
                sv[f][r] = v;
            }
        float pm = -1e30f;
        #pragma unroll
        for (int f = 0; f < 4; f++)
            #pragma unroll
            for (int r = 0; r < 4; r++) pm = fmaxf(pm, sv[f][r]);
        pm = fmaxf(pm, __shfl_xor(pm, 16));
        pm = fmaxf(pm, __shfl_xor(pm, 32));
        // defer-max: if no q-row's max grew by >8, keep m_run (skip rescale).
        // P bounded by e^8; scale cancels in O/l. Wave-uniform branch.
        bool defer = __all(pm <= m_run + 8.0f);
        float p[4][4];
        float ls = 0.f;
        if (defer) {
            #pragma unroll
            for (int f = 0; f < 4; f++)
                #pragma unroll
                for (int r = 0; r < 4; r++) {
                    p[f][r] = __expf(sv[f][r] - m_run);
                    ls += p[f][r];
                }
            ls += __shfl_xor(ls, 16);
            ls += __shfl_xor(ls, 32);
            l_run += ls;
        } else {
            float mnew = fmaxf(m_run, pm);
            float corr = __expf(m_run - mnew);
            #pragma unroll
            for (int f = 0; f < 4; f++)
                #pragma unroll
                for (int r = 0; r < 4; r++) {
                    p[f][r] = __expf(sv[f][r] - mnew);
                    ls += p[f][r];
                }
            ls += __shfl_xor(ls, 16);
            ls += __shfl_xor(ls, 32);
            l_run = l_run * corr + ls;
            m_run = mnew;
            #pragma unroll
            for (int r = 0; r < 4; r++) {
                float cr = __shfl(corr, (lane & 48) | (g * 4 + r));
                #pragma unroll
                for (int f = 0; f < 4; f++) oacc[f][r] *= cr;
            }
        }
        #pragma unroll
        for (int f = 0; f < 4; f++)
            #pragma unroll
            for (int rp = 0; rp < 2; rp++) {
                int ue = f * 16 + g * 4 + rp * 2;
                unsigned int pk = (unsigned int)f2bf(p[f][rp * 2])
                                | ((unsigned int)f2bf(p[f][rp * 2 + 1]) << 16);
                *(unsigned int*)(void*)(Pw + q * 128 + ((ue * 2) ^ ((q & 7) << 4))) = pk;
            }
        #pragma unroll
        for (int ks = 0; ks < 2; ks++) {
            int kb = ks * 64 + (g << 4);
            short8 pa = *(const short8*)(const void*)(Pw + q * 128 + (kb ^ ((q & 7) << 4)));
            #pragma unroll
            for (int f = 0; f < 4; f++) {
                int s = f * 16 + q;
                short8 vf = *(const short8*)(const void*)(Vb[kt] + s * 128 + (kb ^ ((s & 7) << 4)));
                oacc[f] = __builtin_amdgcn_mfma_f32_16x16x32_bf16(pa, vf, oacc[f], 0, 0, 0);
            }
        }
    }
    float inv = 1.0f / l_run;
    #pragma unroll
    for (int r = 0; r < 4; r++) {
        float ir = __shfl(inv, (lane & 48) | (g * 4 + r));
        int row_g = b * T_SEQ + qt * 64 + wave * 16 + g * 4 + r;
        #pragma unroll
        for (int f = 0; f < 4; f++) {
            size_t xi = (size_t)row_g * DMODEL + hh * HSZ + f * 16 + q;
            x[xi] += oacc[f][r] * ir;
        }
    }
}

// ---------------------------------------------------------------------------
// Loss: reduce per-strip {max,sumexp} partials -> nll[row]; then mean
// ---------------------------------------------------------------------------
__global__ __launch_bounds__(256) void loss_reduce_kernel(
    const float* __restrict__ pmax, const float* __restrict__ psum,
    const float* __restrict__ logits, const int* __restrict__ targets,
    float* __restrict__ nll)
{
    int row = blockIdx.x, tid = threadIdx.x;
    const float* pm = pmax + (size_t)row * NSTRIPS;
    const float* ps = psum + (size_t)row * NSTRIPS;
    float M = -1e30f, S = 0.f;
    for (int i = tid; i < NSTRIPS; i += 256) {
        float m2 = pm[i], s2 = ps[i];
        float nm = fmaxf(M, m2);
        S = S * __expf(M - nm) + s2 * __expf(m2 - nm);
        M = nm;
    }
    __shared__ float Ms[256], Ss[256];
    Ms[tid] = M; Ss[tid] = S;
    __syncthreads();
    for (int o = 128; o > 0; o >>= 1) {
        if (tid < o) {
            float m1 = Ms[tid], s1 = Ss[tid];
            float m2 = Ms[tid + o], s2 = Ss[tid + o];
            float nm = fmaxf(m1, m2);
            Ss[tid] = s1 * __expf(m1 - nm) + s2 * __expf(m2 - nm);
            Ms[tid] = nm;
        }
        __syncthreads();
    }
    if (tid == 0)
        nll[row] = logf(Ss[0]) + Ms[0] - logits[(size_t)row * VOCAB + targets[row]];
}

__global__ __launch_bounds__(256) void loss2_kernel(
    const float* __restrict__ nll, float* __restrict__ out)
{
    int tid = threadIdx.x;
    float s = 0.f;
    for (int i = tid; i < MROWS; i += 256) s += nll[i];
    __shared__ float red[256];
    red[tid] = s;
    __syncthreads();
    for (int o = 128; o > 0; o >>= 1) {
        if (tid < o) red[tid] += red[tid + o];
        __syncthreads();
    }
    if (tid == 0) out[0] = red[0] * (1.0f / MROWS);
}

// ---------------------------------------------------------------------------
extern "C" void kernel_launch(void* const* d_in, const int* in_sizes, int n_in,
                              void* d_out, int out_size, void* d_ws, size_t ws_size,
                              hipStream_t stream)
{
    const int*   idx  = (const int*)d_in[0];
    const int*   tgt  = (const int*)d_in[1];
    const float* tok  = (const float*)d_in[2];
    const float* pos  = (const float*)d_in[3];
    const float* Wq   = (const float*)d_in[4];
    const float* Wk   = (const float*)d_in[5];
    const float* Wv   = (const float*)d_in[6];
    const float* ln1g = (const float*)d_in[7];
    const float* ln1b = (const float*)d_in[8];
    const float* ln2g = (const float*)d_in[9];
    const float* ln2b = (const float*)d_in[10];
    const float* fc1w = (const float*)d_in[11];
    const float* fc1b = (const float*)d_in[12];
    const float* fc2w = (const float*)d_in[13];
    const float* fc2b = (const float*)d_in[14];
    const float* lnfg = (const float*)d_in[15];
    const float* lnfb = (const float*)d_in[16];
    const float* lmw  = (const float*)d_in[17];
    const float* lmb  = (const float*)d_in[18];

    char* ws = (char*)d_ws;
    float*          x    = (float*)(ws + 0);                  // 8.39 MB
    unsigned short* h    = (unsigned short*)(ws + 8388608);   // 4.19 MB
    unsigned short* qkv  = (unsigned short*)(ws + 12582912);  // 12.58 MB
    unsigned short* vt   = (unsigned short*)(ws + 25165824);  // 4.19 MB
    unsigned short* mid  = (unsigned short*)(ws + 29360128);  // 16.78 MB
    float*          nll  = (float*)(ws + 46137344);           // 8 KB
    float*          fc2p = (float*)(ws + 46145536);           // 16.78 MB
    unsigned short* lmwt = (unsigned short*)(ws + 62922752);  // 103.02 MB
    float*          pmax = fc2p;                              // reuse (free by lm)
    float*          psum = fc2p + (size_t)MROWS * NSTRIPS;
    const size_t UP_NEED = 442769408ull;
    bool upfront = (ws_size >= UP_NEED);
    unsigned short* qkvt = (unsigned short*)(ws + 165945344);
    unsigned short* fc1t, * fc2t;
    long qkvt_l, fc1t_l, fc2t_l;
    if (upfront) {
        fc1t = (unsigned short*)(ws + 241442816);
        fc2t = (unsigned short*)(ws + 342106112);
        qkvt_l = 3072 * 1024; fc1t_l = (long)FF * 1024; fc2t_l = (long)1024 * FF;
    } else {
        fc1t = (unsigned short*)(ws + 172236800);
        fc2t = (unsigned short*)(ws + 180625408);
        qkvt_l = 0; fc1t_l = 0; fc2t_l = 0;
    }
    float* logits = (float*)d_out;
    float* lossp  = logits + (size_t)MROWS * VOCAB;

    const long WQKV_L = (long)NHEAD * DMODEL * HSZ;
    if (upfront) {
        qkvpack64_kernel<<<dim3(16, 1, 48 * NLAYER), 256, 0, stream>>>(
            Wq, Wk, Wv, qkvt, WQKV_L, qkvt_l);
        wtranspose128_kernel<<<dim3(128, 8, NLAYER), 256, 0, stream>>>(
            fc1w, fc1t, DMODEL, FF, (long)DMODEL * FF, fc1t_l);
        wtranspose128_kernel<<<dim3(32, 32, NLAYER), 256, 0, stream>>>(
            fc2w, fc2t, FF, DMODEL, (long)FF * DMODEL, fc2t_l);
    }
    // LM head transpose: grid.x covers NPAD (reads guarded -> zero pad)
    wtranspose128_kernel<<<dim3(1572, 8, 1), 256, 0, stream>>>(
        lmw, lmwt, DMODEL, VOCAB, 0, 0);

    embed_ln_kernel<<<MROWS, 256, 0, stream>>>(idx, tok, pos, ln1g, ln1b, x, h);

    for (int l = 0; l < NLAYER; l++) {
        unsigned short* qkvt_p = qkvt + (size_t)l * qkvt_l;
        unsigned short* fc1t_p = fc1t + (size_t)l * fc1t_l;
        unsigned short* fc2t_p = fc2t + (size_t)l * fc2t_l;
        if (!upfront) {
            qkvpack64_kernel<<<dim3(16, 1, 48), 256, 0, stream>>>(
                Wq + (size_t)l * WQKV_L, Wk + (size_t)l * WQKV_L,
                Wv + (size_t)l * WQKV_L, qkvt, WQKV_L, 0);
            wtranspose128_kernel<<<dim3(128, 8, 1), 256, 0, stream>>>(
                fc1w + (size_t)l * DMODEL * FF, fc1t, DMODEL, FF, 0, 0);
            wtranspose128_kernel<<<dim3(32, 32, 1), 256, 0, stream>>>(
                fc2w + (size_t)l * FF * DMODEL, fc2t, FF, DMODEL, 0, 0);
        }
        gemm_qkv<<<dim3(16, 24), 256, 0, stream>>>(h, qkvt_p, qkv, vt);
        attn_fused_kernel<<<dim3(4, NHEAD, 8), 256, 0, stream>>>(qkv, vt, x);
        ln_kernel<<<MROWS, 256, 0, stream>>>(x, ln2g + l * DMODEL, ln2b + l * DMODEL, h);
        gemm_fc1<<<dim3(16, 32), 256, 0, stream>>>(h, fc1t_p, fc1b + (size_t)l * FF, mid);
        gemm_fc2<<<dim3(32, 8, 2), 256, 0, stream>>>(mid, fc2t_p, fc2p);
        const float* ng = (l < NLAYER - 1) ? ln1g + (l + 1) * DMODEL : lnfg;
        const float* nb = (l < NLAYER - 1) ? ln1b + (l + 1) * DMODEL : lnfb;
        fc2_merge_ln_kernel<<<MROWS, 256, 0, stream>>>(
            fc2p, fc2b + (size_t)l * DMODEL, ng, nb, x, h);
    }

    gemm_lm<<<dim3(8, 393), 512, 0, stream>>>(h, lmwt, lmb, logits, pmax, psum);

    loss_reduce_kernel<<<MROWS, 256, 0, stream>>>(pmax, psum, logits, tgt, nll);
    loss2_kernel<<<1, 256, 0, stream>>>(nll, lossp);
}

// Round 16
// 1960.544 us; speedup vs baseline: 1.0108x; 1.0108x over previous
//
#include <hip/hip_runtime.h>

#define T_SEQ 256
#define DMODEL 1024
#define NHEAD 16
#define HSZ 64
#define NLAYER 12
#define VOCAB 50257
#define NPAD 50304
#define FF 4096
#define MROWS 2048
#define NSTRIPS 786

using short8 = __attribute__((ext_vector_type(8))) short;
using f32x4  = __attribute__((ext_vector_type(4))) float;

__device__ __forceinline__ float bf2f(unsigned short u) {
    unsigned int x = ((unsigned int)u) << 16;
    return __builtin_bit_cast(float, x);
}
__device__ __forceinline__ unsigned short f2bf(float f) {
    unsigned int u = __builtin_bit_cast(unsigned int, f);
    unsigned int r = (u + 0x7fffu + ((u >> 16) & 1u)) >> 16;
    return (unsigned short)r;
}
__device__ __forceinline__ void async_copy16(const void* g, void* l) {
    __builtin_amdgcn_global_load_lds(
        (const __attribute__((address_space(1))) unsigned int*)g,
        (__attribute__((address_space(3))) unsigned int*)l, 16, 0, 0);
}

// ---------------------------------------------------------------------------
// Shared LN tail
// ---------------------------------------------------------------------------
__device__ __forceinline__ void ln_tail(
    float4 v, const float* __restrict__ g, const float* __restrict__ b,
    int row, int tid, unsigned short* __restrict__ out)
{
    float s  = v.x + v.y + v.z + v.w;
    float ss = v.x * v.x + v.y * v.y + v.z * v.z + v.w * v.w;
    for (int o = 32; o > 0; o >>= 1) {
        s  += __shfl_down(s, o);
        ss += __shfl_down(ss, o);
    }
    __shared__ float ps[4], pss[4];
    int wave = tid >> 6, lane = tid & 63;
    if (lane == 0) { ps[wave] = s; pss[wave] = ss; }
    __syncthreads();
    float st  = ps[0] + ps[1] + ps[2] + ps[3];
    float sst = pss[0] + pss[1] + pss[2] + pss[3];
    float mu  = st * (1.0f / DMODEL);
    float var = sst * (1.0f / DMODEL) - mu * mu;
    float rstd = rsqrtf(var + 1e-5f);
    float4 gv = ((const float4*)g)[tid];
    float4 bv = ((const float4*)b)[tid];
    ushort4 o4;
    o4.x = f2bf((v.x - mu) * rstd * gv.x + bv.x);
    o4.y = f2bf((v.y - mu) * rstd * gv.y + bv.y);
    o4.z = f2bf((v.z - mu) * rstd * gv.z + bv.z);
    o4.w = f2bf((v.w - mu) * rstd * gv.w + bv.w);
    ((ushort4*)out)[(size_t)row * (DMODEL / 4) + tid] = o4;
}

// ---------------------------------------------------------------------------
// Embedding fused with layer-0 ln1
// ---------------------------------------------------------------------------
__global__ __launch_bounds__(256) void embed_ln_kernel(
    const int* __restrict__ idx, const float* __restrict__ tok,
    const float* __restrict__ pos, const float* __restrict__ g,
    const float* __restrict__ b, float* __restrict__ x,
    unsigned short* __restrict__ h)
{
    int row = blockIdx.x, tid = threadIdx.x;
    int t = row & (T_SEQ - 1);
    int token = idx[row];
    float4 a = ((const float4*)(tok + (size_t)token * DMODEL))[tid];
    float4 p = ((const float4*)(pos + (size_t)t * DMODEL))[tid];
    float4 v;
    v.x = a.x + p.x; v.y = a.y + p.y; v.z = a.z + p.z; v.w = a.w + p.w;
    ((float4*)(x + (size_t)row * DMODEL))[tid] = v;
    ln_tail(v, g, b, row, tid, h);
}

// ---------------------------------------------------------------------------
// Plain LayerNorm (ln2)
// ---------------------------------------------------------------------------
__global__ __launch_bounds__(256) void ln_kernel(
    const float* __restrict__ x, const float* __restrict__ g,
    const float* __restrict__ b, unsigned short* __restrict__ out)
{
    int row = blockIdx.x, tid = threadIdx.x;
    float4 v = ((const float4*)(x + (size_t)row * DMODEL))[tid];
    ln_tail(v, g, b, row, tid, out);
}

// ---------------------------------------------------------------------------
// fc2 partial merge + residual + NEXT layer's ln1 (or lnf), fused
// ---------------------------------------------------------------------------
__global__ __launch_bounds__(256) void fc2_merge_ln_kernel(
    const float* __restrict__ part, const float* __restrict__ bias,
    const float* __restrict__ g, const float* __restrict__ b,
    float* __restrict__ x, unsigned short* __restrict__ h)
{
    int row = blockIdx.x, tid = threadIdx.x;
    size_t o = (size_t)row * (DMODEL / 4) + tid;
    float4 p0 = ((const float4*)part)[o];
    float4 p1 = ((const float4*)part)[o + MROWS * (DMODEL / 4)];
    float4 bv = ((const float4*)bias)[tid];
    float4 v = ((float4*)x)[o];
    v.x += p0.x + p1.x + bv.x;
    v.y += p0.y + p1.y + bv.y;
    v.z += p0.z + p1.z + bv.z;
    v.w += p0.w + p1.w + bv.w;
    ((float4*)x)[o] = v;
    ln_tail(v, g, b, row, tid, h);
}

// ---------------------------------------------------------------------------
// 64x64 weight transpose: in [R,C] f32 -> out [C,R] bf16, cols [C,Cout) zero.
// ---------------------------------------------------------------------------
__global__ __launch_bounds__(256) void wtranspose64_kernel(
    const float* __restrict__ in, unsigned short* __restrict__ out,
    int R, int C, long in_l, long out_l)
{
    int lyr = blockIdx.z;
    in  += (size_t)lyr * in_l;
    out += (size_t)lyr * out_l;
    __shared__ float tile[64][65];
    int tx = threadIdx.x & 15, ty = threadIdx.x >> 4;
    int c0 = blockIdx.x * 64, r0 = blockIdx.y * 64;
    #pragma unroll
    for (int i = 0; i < 4; i++) {
        int r = ty + i * 16;
        int c = tx * 4;
        int gc = c0 + c;
        const float* src = in + (size_t)(r0 + r) * C + gc;
        float4 v;
        if (gc + 3 < C) {
            v = *(const float4*)src;
        } else {
            v.x = (gc     < C) ? src[0] : 0.f;
            v.y = (gc + 1 < C) ? src[1] : 0.f;
            v.z = (gc + 2 < C) ? src[2] : 0.f;
            v.w = (gc + 3 < C) ? src[3] : 0.f;
        }
        tile[r][c] = v.x; tile[r][c + 1] = v.y;
        tile[r][c + 2] = v.z; tile[r][c + 3] = v.w;
    }
    __syncthreads();
    int sr = (threadIdx.x & 7) * 8;
    int scb = threadIdx.x >> 3;
    #pragma unroll
    for (int i = 0; i < 2; i++) {
        int c = scb + i * 32;
        unsigned short w[8];
        #pragma unroll
        for (int j = 0; j < 8; j++) w[j] = f2bf(tile[sr + j][c]);
        *(short8*)(void*)(out + (size_t)(c0 + c) * R + r0 + sr) = *(short8*)(void*)w;
    }
}

// ---------------------------------------------------------------------------
// 64x64 QKV weight pack
// ---------------------------------------------------------------------------
__global__ __launch_bounds__(256) void qkvpack64_kernel(
    const float* __restrict__ Wq, const float* __restrict__ Wk,
    const float* __restrict__ Wv, unsigned short* __restrict__ out,
    long w_l, long out_l)
{
    int z = blockIdx.z;
    int lyr = z / 48, r48 = z % 48;
    int seg = r48 >> 4, hh = r48 & 15;
    const float* W = (seg == 0 ? Wq : seg == 1 ? Wk : Wv)
                     + (size_t)lyr * w_l + (size_t)hh * DMODEL * HSZ;
    unsigned short* o = out + (size_t)lyr * out_l
                      + (size_t)(seg * 1024 + hh * 64) * DMODEL;
    __shared__ float tile[64][65];
    int tx = threadIdx.x & 15, ty = threadIdx.x >> 4;
    int d0 = blockIdx.x * 64;
    #pragma unroll
    for (int i = 0; i < 4; i++) {
        int d = ty + i * 16;
        float4 v = *(const float4*)(W + (size_t)(d0 + d) * HSZ + tx * 4);
        tile[d][tx * 4] = v.x; tile[d][tx * 4 + 1] = v.y;
        tile[d][tx * 4 + 2] = v.z; tile[d][tx * 4 + 3] = v.w;
    }
    __syncthreads();
    int db = (threadIdx.x & 7) * 8;
    int sb = threadIdx.x >> 3;
    #pragma unroll
    for (int i = 0; i < 2; i++) {
        int s = sb + i * 32;
        unsigned short w[8];
        #pragma unroll
        for (int j = 0; j < 8; j++) w[j] = f2bf(tile[db + j][s]);
        *(short8*)(void*)(o + (size_t)s * DMODEL + d0 + db) = *(short8*)(void*)w;
    }
}

// ---------------------------------------------------------------------------
// Shared bf16 MFMA GEMM core.
// PIPE=false: single-buffer, 2x __syncthreads per K-step (R12 baseline).
// PIPE=true : T4 counted-vmcnt pipeline — 2 LDS buffers, stage(kt+2) issued
//   after compute(kt), per-step `s_waitcnt vmcnt(NLD)` (never 0 mid-loop) +
//   raw s_barrier (no drain). Each wave waits its OWN stage loads (vmcnt is
//   per-wave), then barrier covers cross-wave completion. (R14: -79us)
// Keep >=2 blocks/CU (R6/R11: 1 barrier domain/CU = -7%).
// ---------------------------------------------------------------------------
template<int MF, int WAVES, int WCOLS, bool QKV, bool RELU, bool RES,
         bool CBF16, bool LOSSP, bool PIPE>
__device__ __forceinline__ void gemm_core(
    const unsigned short* __restrict__ A, int lda,
    const unsigned short* __restrict__ Bt, int ldb,
    const float* __restrict__ bias,
    void* __restrict__ Cv, int ldc,
    const float* __restrict__ res, int ldr,
    int N, int K,
    unsigned short* __restrict__ vtout,
    float* __restrict__ pmax, float* __restrict__ psum)
{
    constexpr int BM = MF * 16 * (WAVES / WCOLS);
    constexpr int BN = 64 * WCOLS;
    constexpr int AJ = (BM * 8) / (WAVES * 64);
    constexpr int BJ = (BN * 8) / (WAVES * 64);
    constexpr int NLD = AJ + BJ;
    constexpr int NBUF = PIPE ? 2 : 1;
    __shared__ __align__(16) char As[NBUF][BM * 128];
    __shared__ __align__(16) char Bs[NBUF][BN * 128];
    int tid = threadIdx.x;
    int wave = tid >> 6, lane = tid & 63;
    int wr = wave / WCOLS, wc = wave % WCOLS;
    int m0 = blockIdx.x * BM, n0 = blockIdx.y * BN;

    f32x4 acc[MF][4];
    #pragma unroll
    for (int m = 0; m < MF; m++)
        #pragma unroll
        for (int n = 0; n < 4; n++)
            acc[m][n] = (f32x4){0.f, 0.f, 0.f, 0.f};

    int ksw = (((lane & 7) ^ (lane >> 3)) << 4);
    int KT = K >> 6;

    auto stage = [&](int kt, int bi) {
        int k0 = kt << 6;
        #pragma unroll
        for (int j = 0; j < AJ; j++) {
            int row = (wave * AJ + j) * 8 + (lane >> 3);
            const char* src = (const char*)A + ((size_t)(m0 + row) * lda + k0) * 2 + ksw;
            async_copy16(src, As[bi] + (wave * AJ + j) * 1024);
        }
        #pragma unroll
        for (int j = 0; j < BJ; j++) {
            int nrow = (wave * BJ + j) * 8 + (lane >> 3);
            const char* src = (const char*)Bt + ((size_t)(n0 + nrow) * ldb + k0) * 2 + ksw;
            async_copy16(src, Bs[bi] + (wave * BJ + j) * 1024);
        }
    };
    auto compute = [&](int bi) {
        #pragma unroll
        for (int ks = 0; ks < 2; ks++) {
            int kb = ks * 64 + ((lane >> 4) << 4);
            short8 a[MF], b[4];
            #pragma unroll
            for (int m = 0; m < MF; m++) {
                int r = wr * (MF * 16) + m * 16 + (lane & 15);
                a[m] = *(const short8*)(const void*)(As[bi] + r * 128 + (kb ^ ((r & 7) << 4)));
            }
            #pragma unroll
            for (int n = 0; n < 4; n++) {
                int c = wc * 64 + n * 16 + (lane & 15);
                b[n] = *(const short8*)(const void*)(Bs[bi] + c * 128 + (kb ^ ((c & 7) << 4)));
            }
            #pragma unroll
            for (int m = 0; m < MF; m++)
                #pragma unroll
                for (int n = 0; n < 4; n++)
                    acc[m][n] = __builtin_amdgcn_mfma_f32_16x16x32_bf16(a[m], b[n], acc[m][n], 0, 0, 0);
        }
    };

    if (PIPE) {
        stage(0, 0);
        stage(1, 1);
        for (int kt = 0; kt < KT; kt++) {
            int cur = kt & 1;
            if (kt + 1 < KT) {
                asm volatile("s_waitcnt vmcnt(%0)" :: "n"(NLD) : "memory");
            } else {
                asm volatile("s_waitcnt vmcnt(0)" ::: "memory");
            }
            __builtin_amdgcn_sched_barrier(0);
            __builtin_amdgcn_s_barrier();
            compute(cur);
            __builtin_amdgcn_s_barrier();
            if (kt + 2 < KT) stage(kt + 2, cur);
        }
    } else {
        for (int kt = 0; kt < KT; kt++) {
            __syncthreads();
            stage(kt, 0);
            __syncthreads();
            compute(0);
        }
    }

    #pragma unroll
    for (int m = 0; m < MF; m++) {
        int rowb = m0 + wr * (MF * 16) + m * 16 + ((lane >> 4) << 2);
        float val[4][4];
        #pragma unroll
        for (int n = 0; n < 4; n++) {
            int col = n0 + wc * 64 + n * 16 + (lane & 15);
            bool okc = (col < N);
            float bi = (bias && okc) ? bias[col] : 0.f;
            #pragma unroll
            for (int r2 = 0; r2 < 4; r2++) {
                float v = acc[m][n][r2] + bi;
                if (RELU) v = fmaxf(v, 0.f);
                int row = rowb + r2;
                if (okc) {
                    if (RES) v += res[(size_t)row * ldr + col];
                    if (QKV && col >= 2048) {
                        int hh = (col - 2048) >> 6, sdim = (col - 2048) & 63;
                        int bb = row >> 8, tt = row & 255;
                        vtout[((((size_t)bb * NHEAD + hh) * HSZ + sdim) * T_SEQ) + tt] = f2bf(v);
                    } else if (CBF16) {
                        ((unsigned short*)Cv)[(size_t)row * ldc + col] = f2bf(v);
                    } else {
                        ((float*)Cv)[(size_t)row * ldc + col] = v;
                    }
                }
                if (LOSSP) val[n][r2] = okc ? v : -1e30f;
            }
        }
        if (LOSSP) {
            #pragma unroll
            for (int r2 = 0; r2 < 4; r2++) {
                float M = fmaxf(fmaxf(val[0][r2], val[1][r2]),
                                fmaxf(val[2][r2], val[3][r2]));
                #pragma unroll
                for (int o = 1; o < 16; o <<= 1) M = fmaxf(M, __shfl_xor(M, o));
                float S = 0.f;
                #pragma unroll
                for (int n = 0; n < 4; n++) S += __expf(val[n][r2] - M);
                #pragma unroll
                for (int o = 1; o < 16; o <<= 1) S += __shfl_xor(S, o);
                if ((lane & 15) == 0) {
                    int row = rowb + r2;
                    int strip = blockIdx.y * WCOLS + wc;
                    pmax[(size_t)row * NSTRIPS + strip] = M;
                    psum[(size_t)row * NSTRIPS + strip] = S;
                }
            }
        }
    }
}

__global__ __launch_bounds__(256) void gemm_qkv(
    const unsigned short* __restrict__ A, const unsigned short* __restrict__ Bt,
    unsigned short* __restrict__ C, unsigned short* __restrict__ vtout)
{
    gemm_core<4, 4, 2, true, false, false, true, false, true>(
        A, DMODEL, Bt, DMODEL, nullptr, C, 3072, nullptr, 0, 3072, DMODEL,
        vtout, nullptr, nullptr);
}

__global__ __launch_bounds__(256) void gemm_fc1(
    const unsigned short* __restrict__ A, const unsigned short* __restrict__ Bt,
    const float* __restrict__ bias, unsigned short* __restrict__ C)
{
    gemm_core<4, 4, 2, false, true, false, true, false, true>(
        A, DMODEL, Bt, DMODEL, bias, C, FF, nullptr, 0, FF, DMODEL,
        nullptr, nullptr, nullptr);
}

__global__ __launch_bounds__(256) void gemm_fc2(
    const unsigned short* __restrict__ A, const unsigned short* __restrict__ Bt,
    float* __restrict__ part)
{
    int z = blockIdx.z;
    gemm_core<2, 4, 2, false, false, false, false, false, true>(
        A + z * 2048, FF, Bt + z * 2048, FF, nullptr,
        part + (size_t)z * MROWS * DMODEL, DMODEL, nullptr, 0,
        DMODEL, 2048, nullptr, nullptr, nullptr);
}

// LM head: 8 waves 256x128 + fused loss partials; NOT piped (dbuf = 96KB ->
// 1 block/CU occupancy cliff; R11 evidence).
__global__ __launch_bounds__(512) void gemm_lm(
    const unsigned short* __restrict__ A, const unsigned short* __restrict__ Bt,
    const float* __restrict__ bias, float* __restrict__ C,
    float* __restrict__ pmax, float* __restrict__ psum)
{
    gemm_core<4, 8, 2, false, false, false, false, true, false>(
        A, DMODEL, Bt, DMODEL, bias, C, VOCAB, nullptr, 0, VOCAB, DMODEL,
        nullptr, pmax, psum);
}

// ---------------------------------------------------------------------------
// Fused flash attention (MFMA), all-resident K/V (R14 exact; defer-max
// reverted — R15 measured it net-negative on this cheap rescale)
// ---------------------------------------------------------------------------
__global__ __launch_bounds__(256) void attn_fused_kernel(
    const unsigned short* __restrict__ qkv, const unsigned short* __restrict__ vt,
    float* __restrict__ x)
{
    int qt = blockIdx.x, hh = blockIdx.y, b = blockIdx.z;
    int tid = threadIdx.x;
    int wave = tid >> 6, lane = tid & 63;
    int g = lane >> 4, q = lane & 15;

    __shared__ __align__(16) char Kb[4][8192];
    __shared__ __align__(16) char Vb[4][8192];
    __shared__ __align__(16) char Plds[4][2048];

    int qrow = b * T_SEQ + qt * 64 + wave * 16 + q;
    const char* qp = (const char*)qkv + ((size_t)qrow * 3072 + hh * HSZ) * 2;
    short8 qreg[2];
    qreg[0] = *(const short8*)(const void*)(qp + (g << 4));
    qreg[1] = *(const short8*)(const void*)(qp + 64 + (g << 4));

    char* Pw = Plds[wave];

    f32x4 oacc[4];
    #pragma unroll
    for (int f = 0; f < 4; f++) oacc[f] = (f32x4){0.f, 0.f, 0.f, 0.f};
    float m_run = -1e30f, l_run = 0.f;

    int srow = wave * 8 + (lane >> 3);
    int sbyte = ((lane & 7) << 4) ^ ((srow & 7) << 4);

    for (int kt = 0; kt <= qt; kt++) {
        #pragma unroll
        for (int c = 0; c < 2; c++) {
            int row = c * 32 + srow;
            const char* src = (const char*)qkv +
                ((size_t)(b * T_SEQ + kt * 64 + row) * 3072 + 1024 + hh * HSZ) * 2 + sbyte;
            async_copy16(src, Kb[kt] + c * 4096 + wave * 1024);
        }
        #pragma unroll
        for (int c = 0; c < 2; c++) {
            int row = c * 32 + srow;
            const char* src = (const char*)vt +
                (((size_t)(b * NHEAD + hh) * HSZ + row) * T_SEQ + kt * 64) * 2 + sbyte;
            async_copy16(src, Vb[kt] + c * 4096 + wave * 1024);
        }
    }
    __syncthreads();

    for (int kt = 0; kt <= qt; kt++) {
        f32x4 sacc[4];
        #pragma unroll
        for (int f = 0; f < 4; f++) sacc[f] = (f32x4){0.f, 0.f, 0.f, 0.f};
        #pragma unroll
        for (int ks = 0; ks < 2; ks++) {
            int kb = ks * 64 + (g << 4);
            #pragma unroll
            for (int f = 0; f < 4; f++) {
                int u = f * 16 + q;
                short8 kf = *(const short8*)(const void*)(Kb[kt] + u * 128 + (kb ^ ((u & 7) << 4)));
                sacc[f] = __builtin_amdgcn_mfma_f32_16x16x32_bf16(kf, qreg[ks], sacc[f], 0, 0, 0);
            }
        }
        float sv[4][4];
        #pragma unroll
        for (int f = 0; f < 4; f++)
            #pragma unroll
            for (int r = 0; r < 4; r++) {
                float v = sacc[f][r] * 0.125f;
                if (kt == qt) {
                    int u_loc = f * 16 + g * 4 + r;
                    if (u_loc > wave * 16 + q) v = -1e30f;
                }
                sv[f][r] = v;
            }
        float pm = -1e30f;
        #pragma unroll
        for (int f = 0; f < 4; f++)
            #pragma unroll
            for (int r = 0; r < 4; r++) pm = fmaxf(pm, sv[f][r]);
        pm = fmaxf(pm, __shfl_xor(pm, 16));
        pm = fmaxf(pm, __shfl_xor(pm, 32));
        float mnew = fmaxf(m_run, pm);
        float corr = __expf(m_run - mnew);
        float p[4][4];
        float ls = 0.f;
        #pragma unroll
        for (int f = 0; f < 4; f++)
            #pragma unroll
            for (int r = 0; r < 4; r++) {
                p[f][r] = __expf(sv[f][r] - mnew);
                ls += p[f][r];
            }
        ls += __shfl_xor(ls, 16);
        ls += __shfl_xor(ls, 32);
        l_run = l_run * corr + ls;
        m_run = mnew;
        #pragma unroll
        for (int r = 0; r < 4; r++) {
            float cr = __shfl(corr, (lane & 48) | (g * 4 + r));
            #pragma unroll
            for (int f = 0; f < 4; f++) oacc[f][r] *= cr;
        }
        #pragma unroll
        for (int f = 0; f < 4; f++)
            #pragma unroll
            for (int rp = 0; rp < 2; rp++) {
                int ue = f * 16 + g * 4 + rp * 2;
                unsigned int pk = (unsigned int)f2bf(p[f][rp * 2])
                                | ((unsigned int)f2bf(p[f][rp * 2 + 1]) << 16);
                *(unsigned int*)(void*)(Pw + q * 128 + ((ue * 2) ^ ((q & 7) << 4))) = pk;
            }
        #pragma unroll
        for (int ks = 0; ks < 2; ks++) {
            int kb = ks * 64 + (g << 4);
            short8 pa = *(const short8*)(const void*)(Pw + q * 128 + (kb ^ ((q & 7) << 4)));
            #pragma unroll
            for (int f = 0; f < 4; f++) {
                int s = f * 16 + q;
                short8 vf = *(const short8*)(const void*)(Vb[kt] + s * 128 + (kb ^ ((s & 7) << 4)));
                oacc[f] = __builtin_amdgcn_mfma_f32_16x16x32_bf16(pa, vf, oacc[f], 0, 0, 0);
            }
        }
    }
    float inv = 1.0f / l_run;
    #pragma unroll
    for (int r = 0; r < 4; r++) {
        float ir = __shfl(inv, (lane & 48) | (g * 4 + r));
        int row_g = b * T_SEQ + qt * 64 + wave * 16 + g * 4 + r;
        #pragma unroll
        for (int f = 0; f < 4; f++) {
            size_t xi = (size_t)row_g * DMODEL + hh * HSZ + f * 16 + q;
            x[xi] += oacc[f][r] * ir;
        }
    }
}

// ---------------------------------------------------------------------------
// Loss: reduce per-strip {max,sumexp} partials -> nll[row]; then mean
// ---------------------------------------------------------------------------
__global__ __launch_bounds__(256) void loss_reduce_kernel(
    const float* __restrict__ pmax, const float* __restrict__ psum,
    const float* __restrict__ logits, const int* __restrict__ targets,
    float* __restrict__ nll)
{
    int row = blockIdx.x, tid = threadIdx.x;
    const float* pm = pmax + (size_t)row * NSTRIPS;
    const float* ps = psum + (size_t)row * NSTRIPS;
    float M = -1e30f, S = 0.f;
    for (int i = tid; i < NSTRIPS; i += 256) {
        float m2 = pm[i], s2 = ps[i];
        float nm = fmaxf(M, m2);
        S = S * __expf(M - nm) + s2 * __expf(m2 - nm);
        M = nm;
    }
    __shared__ float Ms[256], Ss[256];
    Ms[tid] = M; Ss[tid] = S;
    __syncthreads();
    for (int o = 128; o > 0; o >>= 1) {
        if (tid < o) {
            float m1 = Ms[tid], s1 = Ss[tid];
            float m2 = Ms[tid + o], s2 = Ss[tid + o];
            float nm = fmaxf(m1, m2);
            Ss[tid] = s1 * __expf(m1 - nm) + s2 * __expf(m2 - nm);
            Ms[tid] = nm;
        }
        __syncthreads();
    }
    if (tid == 0)
        nll[row] = logf(Ss[0]) + Ms[0] - logits[(size_t)row * VOCAB + targets[row]];
}

__global__ __launch_bounds__(256) void loss2_kernel(
    const float* __restrict__ nll, float* __restrict__ out)
{
    int tid = threadIdx.x;
    float s = 0.f;
    for (int i = tid; i < MROWS; i += 256) s += nll[i];
    __shared__ float red[256];
    red[tid] = s;
    __syncthreads();
    for (int o = 128; o > 0; o >>= 1) {
        if (tid < o) red[tid] += red[tid + o];
        __syncthreads();
    }
    if (tid == 0) out[0] = red[0] * (1.0f / MROWS);
}

// ---------------------------------------------------------------------------
extern "C" void kernel_launch(void* const* d_in, const int* in_sizes, int n_in,
                              void* d_out, int out_size, void* d_ws, size_t ws_size,
                              hipStream_t stream)
{
    const int*   idx  = (const int*)d_in[0];
    const int*   tgt  = (const int*)d_in[1];
    const float* tok  = (const float*)d_in[2];
    const float* pos  = (const float*)d_in[3];
    const float* Wq   = (const float*)d_in[4];
    const float* Wk   = (const float*)d_in[5];
    const float* Wv   = (const float*)d_in[6];
    const float* ln1g = (const float*)d_in[7];
    const float* ln1b = (const float*)d_in[8];
    const float* ln2g = (const float*)d_in[9];
    const float* ln2b = (const float*)d_in[10];
    const float* fc1w = (const float*)d_in[11];
    const float* fc1b = (const float*)d_in[12];
    const float* fc2w = (const float*)d_in[13];
    const float* fc2b = (const float*)d_in[14];
    const float* lnfg = (const float*)d_in[15];
    const float* lnfb = (const float*)d_in[16];
    const float* lmw  = (const float*)d_in[17];
    const float* lmb  = (const float*)d_in[18];

    char* ws = (char*)d_ws;
    float*          x    = (float*)(ws + 0);                  // 8.39 MB
    unsigned short* h    = (unsigned short*)(ws + 8388608);   // 4.19 MB
    unsigned short* qkv  = (unsigned short*)(ws + 12582912);  // 12.58 MB
    unsigned short* vt   = (unsigned short*)(ws + 25165824);  // 4.19 MB
    unsigned short* mid  = (unsigned short*)(ws + 29360128);  // 16.78 MB
    float*          nll  = (float*)(ws + 46137344);           // 8 KB
    float*          fc2p = (float*)(ws + 46145536);           // 16.78 MB
    unsigned short* lmwt = (unsigned short*)(ws + 62922752);  // 103.02 MB
    float*          pmax = fc2p;                              // reuse (free by lm)
    float*          psum = fc2p + (size_t)MROWS * NSTRIPS;
    const size_t UP_NEED = 442769408ull;
    bool upfront = (ws_size >= UP_NEED);
    unsigned short* qkvt = (unsigned short*)(ws + 165945344);
    unsigned short* fc1t, * fc2t;
    long qkvt_l, fc1t_l, fc2t_l;
    if (upfront) {
        fc1t = (unsigned short*)(ws + 241442816);
        fc2t = (unsigned short*)(ws + 342106112);
        qkvt_l = 3072 * 1024; fc1t_l = (long)FF * 1024; fc2t_l = (long)1024 * FF;
    } else {
        fc1t = (unsigned short*)(ws + 172236800);
        fc2t = (unsigned short*)(ws + 180625408);
        qkvt_l = 0; fc1t_l = 0; fc2t_l = 0;
    }
    float* logits = (float*)d_out;
    float* lossp  = logits + (size_t)MROWS * VOCAB;

    const long WQKV_L = (long)NHEAD * DMODEL * HSZ;
    if (upfront) {
        qkvpack64_kernel<<<dim3(16, 1, 48 * NLAYER), 256, 0, stream>>>(
            Wq, Wk, Wv, qkvt, WQKV_L, qkvt_l);
        wtranspose64_kernel<<<dim3(64, 16, NLAYER), 256, 0, stream>>>(
            fc1w, fc1t, DMODEL, FF, (long)DMODEL * FF, fc1t_l);
        wtranspose64_kernel<<<dim3(16, 64, NLAYER), 256, 0, stream>>>(
            fc2w, fc2t, FF, DMODEL, (long)FF * DMODEL, fc2t_l);
    }
    wtranspose64_kernel<<<dim3(786, 16, 1), 256, 0, stream>>>(
        lmw, lmwt, DMODEL, VOCAB, 0, 0);

    embed_ln_kernel<<<MROWS, 256, 0, stream>>>(idx, tok, pos, ln1g, ln1b, x, h);

    for (int l = 0; l < NLAYER; l++) {
        unsigned short* qkvt_p = qkvt + (size_t)l * qkvt_l;
        unsigned short* fc1t_p = fc1t + (size_t)l * fc1t_l;
        unsigned short* fc2t_p = fc2t + (size_t)l * fc2t_l;
        if (!upfront) {
            qkvpack64_kernel<<<dim3(16, 1, 48), 256, 0, stream>>>(
                Wq + (size_t)l * WQKV_L, Wk + (size_t)l * WQKV_L,
                Wv + (size_t)l * WQKV_L, qkvt, WQKV_L, 0);
            wtranspose64_kernel<<<dim3(64, 16, 1), 256, 0, stream>>>(
                fc1w + (size_t)l * DMODEL * FF, fc1t, DMODEL, FF, 0, 0);
            wtranspose64_kernel<<<dim3(16, 64, 1), 256, 0, stream>>>(
                fc2w + (size_t)l * FF * DMODEL, fc2t, FF, DMODEL, 0, 0);
        }
        gemm_qkv<<<dim3(16, 24), 256, 0, stream>>>(h, qkvt_p, qkv, vt);
        attn_fused_kernel<<<dim3(4, NHEAD, 8), 256, 0, stream>>>(qkv, vt, x);
        ln_kernel<<<MROWS, 256, 0, stream>>>(x, ln2g + l * DMODEL, ln2b + l * DMODEL, h);
        gemm_fc1<<<dim3(16, 32), 256, 0, stream>>>(h, fc1t_p, fc1b + (size_t)l * FF, mid);
        gemm_fc2<<<dim3(32, 8, 2), 256, 0, stream>>>(mid, fc2t_p, fc2p);
        const float* ng = (l < NLAYER - 1) ? ln1g + (l + 1) * DMODEL : lnfg;
        const float* nb = (l < NLAYER - 1) ? ln1b + (l + 1) * DMODEL : lnfb;
        fc2_merge_ln_kernel<<<MROWS, 256, 0, stream>>>(
            fc2p, fc2b + (size_t)l * DMODEL, ng, nb, x, h);
    }

    gemm_lm<<<dim3(8, 393), 512, 0, stream>>>(h, lmwt, lmb, logits, pmax, psum);

    loss_reduce_kernel<<<MROWS, 256, 0, stream>>>(pmax, psum, logits, tgt, nll);
    loss2_kernel<<<1, 256, 0, stream>>>(nll, lossp);
}

// Round 17
// 1920.735 us; speedup vs baseline: 1.0317x; 1.0207x over previous
//
#include <hip/hip_runtime.h>

#define T_SEQ 256
#define DMODEL 1024
#define NHEAD 16
#define HSZ 64
#define NLAYER 12
#define VOCAB 50257
#define NPAD 50304
#define FF 4096
#define MROWS 2048
#define NSTRIPS 786

using short8 = __attribute__((ext_vector_type(8))) short;
using f32x4  = __attribute__((ext_vector_type(4))) float;

__device__ __forceinline__ float bf2f(unsigned short u) {
    unsigned int x = ((unsigned int)u) << 16;
    return __builtin_bit_cast(float, x);
}
__device__ __forceinline__ unsigned short f2bf(float f) {
    unsigned int u = __builtin_bit_cast(unsigned int, f);
    unsigned int r = (u + 0x7fffu + ((u >> 16) & 1u)) >> 16;
    return (unsigned short)r;
}
__device__ __forceinline__ void async_copy16(const void* g, void* l) {
    __builtin_amdgcn_global_load_lds(
        (const __attribute__((address_space(1))) unsigned int*)g,
        (__attribute__((address_space(3))) unsigned int*)l, 16, 0, 0);
}

// ---------------------------------------------------------------------------
// Shared LN tail
// ---------------------------------------------------------------------------
__device__ __forceinline__ void ln_tail(
    float4 v, const float* __restrict__ g, const float* __restrict__ b,
    int row, int tid, unsigned short* __restrict__ out)
{
    float s  = v.x + v.y + v.z + v.w;
    float ss = v.x * v.x + v.y * v.y + v.z * v.z + v.w * v.w;
    for (int o = 32; o > 0; o >>= 1) {
        s  += __shfl_down(s, o);
        ss += __shfl_down(ss, o);
    }
    __shared__ float ps[4], pss[4];
    int wave = tid >> 6, lane = tid & 63;
    if (lane == 0) { ps[wave] = s; pss[wave] = ss; }
    __syncthreads();
    float st  = ps[0] + ps[1] + ps[2] + ps[3];
    float sst = pss[0] + pss[1] + pss[2] + pss[3];
    float mu  = st * (1.0f / DMODEL);
    float var = sst * (1.0f / DMODEL) - mu * mu;
    float rstd = rsqrtf(var + 1e-5f);
    float4 gv = ((const float4*)g)[tid];
    float4 bv = ((const float4*)b)[tid];
    ushort4 o4;
    o4.x = f2bf((v.x - mu) * rstd * gv.x + bv.x);
    o4.y = f2bf((v.y - mu) * rstd * gv.y + bv.y);
    o4.z = f2bf((v.z - mu) * rstd * gv.z + bv.z);
    o4.w = f2bf((v.w - mu) * rstd * gv.w + bv.w);
    ((ushort4*)out)[(size_t)row * (DMODEL / 4) + tid] = o4;
}

// ---------------------------------------------------------------------------
// Embedding fused with layer-0 ln1
// ---------------------------------------------------------------------------
__global__ __launch_bounds__(256) void embed_ln_kernel(
    const int* __restrict__ idx, const float* __restrict__ tok,
    const float* __restrict__ pos, const float* __restrict__ g,
    const float* __restrict__ b, float* __restrict__ x,
    unsigned short* __restrict__ h)
{
    int row = blockIdx.x, tid = threadIdx.x;
    int t = row & (T_SEQ - 1);
    int token = idx[row];
    float4 a = ((const float4*)(tok + (size_t)token * DMODEL))[tid];
    float4 p = ((const float4*)(pos + (size_t)t * DMODEL))[tid];
    float4 v;
    v.x = a.x + p.x; v.y = a.y + p.y; v.z = a.z + p.z; v.w = a.w + p.w;
    ((float4*)(x + (size_t)row * DMODEL))[tid] = v;
    ln_tail(v, g, b, row, tid, h);
}

// ---------------------------------------------------------------------------
// Plain LayerNorm (ln2)
// ---------------------------------------------------------------------------
__global__ __launch_bounds__(256) void ln_kernel(
    const float* __restrict__ x, const float* __restrict__ g,
    const float* __restrict__ b, unsigned short* __restrict__ out)
{
    int row = blockIdx.x, tid = threadIdx.x;
    float4 v = ((const float4*)(x + (size_t)row * DMODEL))[tid];
    ln_tail(v, g, b, row, tid, out);
}

// ---------------------------------------------------------------------------
// fc2 partial merge + residual + NEXT layer's ln1 (or lnf), fused
// ---------------------------------------------------------------------------
__global__ __launch_bounds__(256) void fc2_merge_ln_kernel(
    const float* __restrict__ part, const float* __restrict__ bias,
    const float* __restrict__ g, const float* __restrict__ b,
    float* __restrict__ x, unsigned short* __restrict__ h)
{
    int row = blockIdx.x, tid = threadIdx.x;
    size_t o = (size_t)row * (DMODEL / 4) + tid;
    float4 p0 = ((const float4*)part)[o];
    float4 p1 = ((const float4*)part)[o + MROWS * (DMODEL / 4)];
    float4 bv = ((const float4*)bias)[tid];
    float4 v = ((float4*)x)[o];
    v.x += p0.x + p1.x + bv.x;
    v.y += p0.y + p1.y + bv.y;
    v.z += p0.z + p1.z + bv.z;
    v.w += p0.w + p1.w + bv.w;
    ((float4*)x)[o] = v;
    ln_tail(v, g, b, row, tid, h);
}

// ---------------------------------------------------------------------------
// 64x64 weight transpose: in [R,C] f32 -> out [C,R] bf16, cols [C,Cout) zero.
// ---------------------------------------------------------------------------
__global__ __launch_bounds__(256) void wtranspose64_kernel(
    const float* __restrict__ in, unsigned short* __restrict__ out,
    int R, int C, long in_l, long out_l)
{
    int lyr = blockIdx.z;
    in  += (size_t)lyr * in_l;
    out += (size_t)lyr * out_l;
    __shared__ float tile[64][65];
    int tx = threadIdx.x & 15, ty = threadIdx.x >> 4;
    int c0 = blockIdx.x * 64, r0 = blockIdx.y * 64;
    #pragma unroll
    for (int i = 0; i < 4; i++) {
        int r = ty + i * 16;
        int c = tx * 4;
        int gc = c0 + c;
        const float* src = in + (size_t)(r0 + r) * C + gc;
        float4 v;
        if (gc + 3 < C) {
            v = *(const float4*)src;
        } else {
            v.x = (gc     < C) ? src[0] : 0.f;
            v.y = (gc + 1 < C) ? src[1] : 0.f;
            v.z = (gc + 2 < C) ? src[2] : 0.f;
            v.w = (gc + 3 < C) ? src[3] : 0.f;
        }
        tile[r][c] = v.x; tile[r][c + 1] = v.y;
        tile[r][c + 2] = v.z; tile[r][c + 3] = v.w;
    }
    __syncthreads();
    int sr = (threadIdx.x & 7) * 8;
    int scb = threadIdx.x >> 3;
    #pragma unroll
    for (int i = 0; i < 2; i++) {
        int c = scb + i * 32;
        unsigned short w[8];
        #pragma unroll
        for (int j = 0; j < 8; j++) w[j] = f2bf(tile[sr + j][c]);
        *(short8*)(void*)(out + (size_t)(c0 + c) * R + r0 + sr) = *(short8*)(void*)w;
    }
}

// ---------------------------------------------------------------------------
// 64x64 QKV weight pack
// ---------------------------------------------------------------------------
__global__ __launch_bounds__(256) void qkvpack64_kernel(
    const float* __restrict__ Wq, const float* __restrict__ Wk,
    const float* __restrict__ Wv, unsigned short* __restrict__ out,
    long w_l, long out_l)
{
    int z = blockIdx.z;
    int lyr = z / 48, r48 = z % 48;
    int seg = r48 >> 4, hh = r48 & 15;
    const float* W = (seg == 0 ? Wq : seg == 1 ? Wk : Wv)
                     + (size_t)lyr * w_l + (size_t)hh * DMODEL * HSZ;
    unsigned short* o = out + (size_t)lyr * out_l
                      + (size_t)(seg * 1024 + hh * 64) * DMODEL;
    __shared__ float tile[64][65];
    int tx = threadIdx.x & 15, ty = threadIdx.x >> 4;
    int d0 = blockIdx.x * 64;
    #pragma unroll
    for (int i = 0; i < 4; i++) {
        int d = ty + i * 16;
        float4 v = *(const float4*)(W + (size_t)(d0 + d) * HSZ + tx * 4);
        tile[d][tx * 4] = v.x; tile[d][tx * 4 + 1] = v.y;
        tile[d][tx * 4 + 2] = v.z; tile[d][tx * 4 + 3] = v.w;
    }
    __syncthreads();
    int db = (threadIdx.x & 7) * 8;
    int sb = threadIdx.x >> 3;
    #pragma unroll
    for (int i = 0; i < 2; i++) {
        int s = sb + i * 32;
        unsigned short w[8];
        #pragma unroll
        for (int j = 0; j < 8; j++) w[j] = f2bf(tile[db + j][s]);
        *(short8*)(void*)(o + (size_t)s * DMODEL + d0 + db) = *(short8*)(void*)w;
    }
}

// ---------------------------------------------------------------------------
// Shared bf16 MFMA GEMM core.
// PIPE=true: T4 counted-vmcnt pipeline (R14, -79us proven).
// Keep >=2 blocks/CU (R6/R11: 1 barrier domain/CU = -7%).
// 8-wave 128x128 variant (<2,8,2>): 16 waves/CU for latency hiding
// (R9 evidence: lm 8-wave at higher occupancy hit 30% MfmaUtil vs 22%).
// ---------------------------------------------------------------------------
template<int MF, int WAVES, int WCOLS, bool QKV, bool RELU, bool RES,
         bool CBF16, bool LOSSP, bool PIPE>
__device__ __forceinline__ void gemm_core(
    const unsigned short* __restrict__ A, int lda,
    const unsigned short* __restrict__ Bt, int ldb,
    const float* __restrict__ bias,
    void* __restrict__ Cv, int ldc,
    const float* __restrict__ res, int ldr,
    int N, int K,
    unsigned short* __restrict__ vtout,
    float* __restrict__ pmax, float* __restrict__ psum)
{
    constexpr int BM = MF * 16 * (WAVES / WCOLS);
    constexpr int BN = 64 * WCOLS;
    constexpr int AJ = (BM * 8) / (WAVES * 64);
    constexpr int BJ = (BN * 8) / (WAVES * 64);
    constexpr int NLD = AJ + BJ;
    constexpr int NBUF = PIPE ? 2 : 1;
    __shared__ __align__(16) char As[NBUF][BM * 128];
    __shared__ __align__(16) char Bs[NBUF][BN * 128];
    int tid = threadIdx.x;
    int wave = tid >> 6, lane = tid & 63;
    int wr = wave / WCOLS, wc = wave % WCOLS;
    int m0 = blockIdx.x * BM, n0 = blockIdx.y * BN;

    f32x4 acc[MF][4];
    #pragma unroll
    for (int m = 0; m < MF; m++)
        #pragma unroll
        for (int n = 0; n < 4; n++)
            acc[m][n] = (f32x4){0.f, 0.f, 0.f, 0.f};

    int ksw = (((lane & 7) ^ (lane >> 3)) << 4);
    int KT = K >> 6;

    auto stage = [&](int kt, int bi) {
        int k0 = kt << 6;
        #pragma unroll
        for (int j = 0; j < AJ; j++) {
            int row = (wave * AJ + j) * 8 + (lane >> 3);
            const char* src = (const char*)A + ((size_t)(m0 + row) * lda + k0) * 2 + ksw;
            async_copy16(src, As[bi] + (wave * AJ + j) * 1024);
        }
        #pragma unroll
        for (int j = 0; j < BJ; j++) {
            int nrow = (wave * BJ + j) * 8 + (lane >> 3);
            const char* src = (const char*)Bt + ((size_t)(n0 + nrow) * ldb + k0) * 2 + ksw;
            async_copy16(src, Bs[bi] + (wave * BJ + j) * 1024);
        }
    };
    auto compute = [&](int bi) {
        #pragma unroll
        for (int ks = 0; ks < 2; ks++) {
            int kb = ks * 64 + ((lane >> 4) << 4);
            short8 a[MF], b[4];
            #pragma unroll
            for (int m = 0; m < MF; m++) {
                int r = wr * (MF * 16) + m * 16 + (lane & 15);
                a[m] = *(const short8*)(const void*)(As[bi] + r * 128 + (kb ^ ((r & 7) << 4)));
            }
            #pragma unroll
            for (int n = 0; n < 4; n++) {
                int c = wc * 64 + n * 16 + (lane & 15);
                b[n] = *(const short8*)(const void*)(Bs[bi] + c * 128 + (kb ^ ((c & 7) << 4)));
            }
            #pragma unroll
            for (int m = 0; m < MF; m++)
                #pragma unroll
                for (int n = 0; n < 4; n++)
                    acc[m][n] = __builtin_amdgcn_mfma_f32_16x16x32_bf16(a[m], b[n], acc[m][n], 0, 0, 0);
        }
    };

    if (PIPE) {
        stage(0, 0);
        stage(1, 1);
        for (int kt = 0; kt < KT; kt++) {
            int cur = kt & 1;
            if (kt + 1 < KT) {
                asm volatile("s_waitcnt vmcnt(%0)" :: "n"(NLD) : "memory");
            } else {
                asm volatile("s_waitcnt vmcnt(0)" ::: "memory");
            }
            __builtin_amdgcn_sched_barrier(0);
            __builtin_amdgcn_s_barrier();
            compute(cur);
            __builtin_amdgcn_s_barrier();
            if (kt + 2 < KT) stage(kt + 2, cur);
        }
    } else {
        for (int kt = 0; kt < KT; kt++) {
            __syncthreads();
            stage(kt, 0);
            __syncthreads();
            compute(0);
        }
    }

    #pragma unroll
    for (int m = 0; m < MF; m++) {
        int rowb = m0 + wr * (MF * 16) + m * 16 + ((lane >> 4) << 2);
        float val[4][4];
        #pragma unroll
        for (int n = 0; n < 4; n++) {
            int col = n0 + wc * 64 + n * 16 + (lane & 15);
            bool okc = (col < N);
            float bi = (bias && okc) ? bias[col] : 0.f;
            #pragma unroll
            for (int r2 = 0; r2 < 4; r2++) {
                float v = acc[m][n][r2] + bi;
                if (RELU) v = fmaxf(v, 0.f);
                int row = rowb + r2;
                if (okc) {
                    if (RES) v += res[(size_t)row * ldr + col];
                    if (QKV && col >= 2048) {
                        int hh = (col - 2048) >> 6, sdim = (col - 2048) & 63;
                        int bb = row >> 8, tt = row & 255;
                        vtout[((((size_t)bb * NHEAD + hh) * HSZ + sdim) * T_SEQ) + tt] = f2bf(v);
                    } else if (CBF16) {
                        ((unsigned short*)Cv)[(size_t)row * ldc + col] = f2bf(v);
                    } else {
                        ((float*)Cv)[(size_t)row * ldc + col] = v;
                    }
                }
                if (LOSSP) val[n][r2] = okc ? v : -1e30f;
            }
        }
        if (LOSSP) {
            #pragma unroll
            for (int r2 = 0; r2 < 4; r2++) {
                float M = fmaxf(fmaxf(val[0][r2], val[1][r2]),
                                fmaxf(val[2][r2], val[3][r2]));
                #pragma unroll
                for (int o = 1; o < 16; o <<= 1) M = fmaxf(M, __shfl_xor(M, o));
                float S = 0.f;
                #pragma unroll
                for (int n = 0; n < 4; n++) S += __expf(val[n][r2] - M);
                #pragma unroll
                for (int o = 1; o < 16; o <<= 1) S += __shfl_xor(S, o);
                if ((lane & 15) == 0) {
                    int row = rowb + r2;
                    int strip = blockIdx.y * WCOLS + wc;
                    pmax[(size_t)row * NSTRIPS + strip] = M;
                    psum[(size_t)row * NSTRIPS + strip] = S;
                }
            }
        }
    }
}

// qkv: 8-wave 128x128 (16 waves/CU), T4-piped
__global__ __launch_bounds__(512) void gemm_qkv(
    const unsigned short* __restrict__ A, const unsigned short* __restrict__ Bt,
    unsigned short* __restrict__ C, unsigned short* __restrict__ vtout)
{
    gemm_core<2, 8, 2, true, false, false, true, false, true>(
        A, DMODEL, Bt, DMODEL, nullptr, C, 3072, nullptr, 0, 3072, DMODEL,
        vtout, nullptr, nullptr);
}

// fc1: 8-wave 128x128 (16 waves/CU), T4-piped
__global__ __launch_bounds__(512) void gemm_fc1(
    const unsigned short* __restrict__ A, const unsigned short* __restrict__ Bt,
    const float* __restrict__ bias, unsigned short* __restrict__ C)
{
    gemm_core<2, 8, 2, false, true, false, true, false, true>(
        A, DMODEL, Bt, DMODEL, bias, C, FF, nullptr, 0, FF, DMODEL,
        nullptr, nullptr, nullptr);
}

// fc2 split-K: stays 4-wave (8-wave BM=128 would give 256 blocks = 1/CU trap)
__global__ __launch_bounds__(256) void gemm_fc2(
    const unsigned short* __restrict__ A, const unsigned short* __restrict__ Bt,
    float* __restrict__ part)
{
    int z = blockIdx.z;
    gemm_core<2, 4, 2, false, false, false, false, false, true>(
        A + z * 2048, FF, Bt + z * 2048, FF, nullptr,
        part + (size_t)z * MROWS * DMODEL, DMODEL, nullptr, 0,
        DMODEL, 2048, nullptr, nullptr, nullptr);
}

// LM head: 8 waves 256x128 + fused loss partials; NOT piped (R11 evidence)
__global__ __launch_bounds__(512) void gemm_lm(
    const unsigned short* __restrict__ A, const unsigned short* __restrict__ Bt,
    const float* __restrict__ bias, float* __restrict__ C,
    float* __restrict__ pmax, float* __restrict__ psum)
{
    gemm_core<4, 8, 2, false, false, false, false, true, false>(
        A, DMODEL, Bt, DMODEL, bias, C, VOCAB, nullptr, 0, VOCAB, DMODEL,
        nullptr, pmax, psum);
}

// ---------------------------------------------------------------------------
// Fused flash attention (MFMA), all-resident K/V (R14/R16 proven)
// ---------------------------------------------------------------------------
__global__ __launch_bounds__(256) void attn_fused_kernel(
    const unsigned short* __restrict__ qkv, const unsigned short* __restrict__ vt,
    float* __restrict__ x)
{
    int qt = blockIdx.x, hh = blockIdx.y, b = blockIdx.z;
    int tid = threadIdx.x;
    int wave = tid >> 6, lane = tid & 63;
    int g = lane >> 4, q = lane & 15;

    __shared__ __align__(16) char Kb[4][8192];
    __shared__ __align__(16) char Vb[4][8192];
    __shared__ __align__(16) char Plds[4][2048];

    int qrow = b * T_SEQ + qt * 64 + wave * 16 + q;
    const char* qp = (const char*)qkv + ((size_t)qrow * 3072 + hh * HSZ) * 2;
    short8 qreg[2];
    qreg[0] = *(const short8*)(const void*)(qp + (g << 4));
    qreg[1] = *(const short8*)(const void*)(qp + 64 + (g << 4));

    char* Pw = Plds[wave];

    f32x4 oacc[4];
    #pragma unroll
    for (int f = 0; f < 4; f++) oacc[f] = (f32x4){0.f, 0.f, 0.f, 0.f};
    float m_run = -1e30f, l_run = 0.f;

    int srow = wave * 8 + (lane >> 3);
    int sbyte = ((lane & 7) << 4) ^ ((srow & 7) << 4);

    for (int kt = 0; kt <= qt; kt++) {
        #pragma unroll
        for (int c = 0; c < 2; c++) {
            int row = c * 32 + srow;
            const char* src = (const char*)qkv +
                ((size_t)(b * T_SEQ + kt * 64 + row) * 3072 + 1024 + hh * HSZ) * 2 + sbyte;
            async_copy16(src, Kb[kt] + c * 4096 + wave * 1024);
        }
        #pragma unroll
        for (int c = 0; c < 2; c++) {
            int row = c * 32 + srow;
            const char* src = (const char*)vt +
                (((size_t)(b * NHEAD + hh) * HSZ + row) * T_SEQ + kt * 64) * 2 + sbyte;
            async_copy16(src, Vb[kt] + c * 4096 + wave * 1024);
        }
    }
    __syncthreads();

    for (int kt = 0; kt <= qt; kt++) {
        f32x4 sacc[4];
        #pragma unroll
        for (int f = 0; f < 4; f++) sacc[f] = (f32x4){0.f, 0.f, 0.f, 0.f};
        #pragma unroll
        for (int ks = 0; ks < 2; ks++) {
            int kb = ks * 64 + (g << 4);
            #pragma unroll
            for (int f = 0; f < 4; f++) {
                int u = f * 16 + q;
                short8 kf = *(const short8*)(const void*)(Kb[kt] + u * 128 + (kb ^ ((u & 7) << 4)));
                sacc[f] = __builtin_amdgcn_mfma_f32_16x16x32_bf16(kf, qreg[ks], sacc[f], 0, 0, 0);
            }
        }
        float sv[4][4];
        #pragma unroll
        for (int f = 0; f < 4; f++)
            #pragma unroll
            for (int r = 0; r < 4; r++) {
                float v = sacc[f][r] * 0.125f;
                if (kt == qt) {
                    int u_loc = f * 16 + g * 4 + r;
                    if (u_loc > wave * 16 + q) v = -1e30f;
                }
                sv[f][r] = v;
            }
        float pm = -1e30f;
        #pragma unroll
        for (int f = 0; f < 4; f++)
            #pragma unroll
            for (int r = 0; r < 4; r++) pm = fmaxf(pm, sv[f][r]);
        pm = fmaxf(pm, __shfl_xor(pm, 16));
        pm = fmaxf(pm, __shfl_xor(pm, 32));
        float mnew = fmaxf(m_run, pm);
        float corr = __expf(m_run - mnew);
        float p[4][4];
        float ls = 0.f;
        #pragma unroll
        for (int f = 0; f < 4; f++)
            #pragma unroll
            for (int r = 0; r < 4; r++) {
                p[f][r] = __expf(sv[f][r] - mnew);
                ls += p[f][r];
            }
        ls += __shfl_xor(ls, 16);
        ls += __shfl_xor(ls, 32);
        l_run = l_run * corr + ls;
        m_run = mnew;
        #pragma unroll
        for (int r = 0; r < 4; r++) {
            float cr = __shfl(corr, (lane & 48) | (g * 4 + r));
            #pragma unroll
            for (int f = 0; f < 4; f++) oacc[f][r] *= cr;
        }
        #pragma unroll
        for (int f = 0; f < 4; f++)
            #pragma unroll
            for (int rp = 0; rp < 2; rp++) {
                int ue = f * 16 + g * 4 + rp * 2;
                unsigned int pk = (unsigned int)f2bf(p[f][rp * 2])
                                | ((unsigned int)f2bf(p[f][rp * 2 + 1]) << 16);
                *(unsigned int*)(void*)(Pw + q * 128 + ((ue * 2) ^ ((q & 7) << 4))) = pk;
            }
        #pragma unroll
        for (int ks = 0; ks < 2; ks++) {
            int kb = ks * 64 + (g << 4);
            short8 pa = *(const short8*)(const void*)(Pw + q * 128 + (kb ^ ((q & 7) << 4)));
            #pragma unroll
            for (int f = 0; f < 4; f++) {
                int s = f * 16 + q;
                short8 vf = *(const short8*)(const void*)(Vb[kt] + s * 128 + (kb ^ ((s & 7) << 4)));
                oacc[f] = __builtin_amdgcn_mfma_f32_16x16x32_bf16(pa, vf, oacc[f], 0, 0, 0);
            }
        }
    }
    float inv = 1.0f / l_run;
    #pragma unroll
    for (int r = 0; r < 4; r++) {
        float ir = __shfl(inv, (lane & 48) | (g * 4 + r));
        int row_g = b * T_SEQ + qt * 64 + wave * 16 + g * 4 + r;
        #pragma unroll
        for (int f = 0; f < 4; f++) {
            size_t xi = (size_t)row_g * DMODEL + hh * HSZ + f * 16 + q;
            x[xi] += oacc[f][r] * ir;
        }
    }
}

// ---------------------------------------------------------------------------
// Loss: reduce per-strip {max,sumexp} partials -> nll[row]; then mean
// ---------------------------------------------------------------------------
__global__ __launch_bounds__(256) void loss_reduce_kernel(
    const float* __restrict__ pmax, const float* __restrict__ psum,
    const float* __restrict__ logits, const int* __restrict__ targets,
    float* __restrict__ nll)
{
    int row = blockIdx.x, tid = threadIdx.x;
    const float* pm = pmax + (size_t)row * NSTRIPS;
    const float* ps = psum + (size_t)row * NSTRIPS;
    float M = -1e30f, S = 0.f;
    for (int i = tid; i < NSTRIPS; i += 256) {
        float m2 = pm[i], s2 = ps[i];
        float nm = fmaxf(M, m2);
        S = S * __expf(M - nm) + s2 * __expf(m2 - nm);
        M = nm;
    }
    __shared__ float Ms[256], Ss[256];
    Ms[tid] = M; Ss[tid] = S;
    __syncthreads();
    for (int o = 128; o > 0; o >>= 1) {
        if (tid < o) {
            float m1 = Ms[tid], s1 = Ss[tid];
            float m2 = Ms[tid + o], s2 = Ss[tid + o];
            float nm = fmaxf(m1, m2);
            Ss[tid] = s1 * __expf(m1 - nm) + s2 * __expf(m2 - nm);
            Ms[tid] = nm;
        }
        __syncthreads();
    }
    if (tid == 0)
        nll[row] = logf(Ss[0]) + Ms[0] - logits[(size_t)row * VOCAB + targets[row]];
}

__global__ __launch_bounds__(256) void loss2_kernel(
    const float* __restrict__ nll, float* __restrict__ out)
{
    int tid = threadIdx.x;
    float s = 0.f;
    for (int i = tid; i < MROWS; i += 256) s += nll[i];
    __shared__ float red[256];
    red[tid] = s;
    __syncthreads();
    for (int o = 128; o > 0; o >>= 1) {
        if (tid < o) red[tid] += red[tid + o];
        __syncthreads();
    }
    if (tid == 0) out[0] = red[0] * (1.0f / MROWS);
}

// ---------------------------------------------------------------------------
extern "C" void kernel_launch(void* const* d_in, const int* in_sizes, int n_in,
                              void* d_out, int out_size, void* d_ws, size_t ws_size,
                              hipStream_t stream)
{
    const int*   idx  = (const int*)d_in[0];
    const int*   tgt  = (const int*)d_in[1];
    const float* tok  = (const float*)d_in[2];
    const float* pos  = (const float*)d_in[3];
    const float* Wq   = (const float*)d_in[4];
    const float* Wk   = (const float*)d_in[5];
    const float* Wv   = (const float*)d_in[6];
    const float* ln1g = (const float*)d_in[7];
    const float* ln1b = (const float*)d_in[8];
    const float* ln2g = (const float*)d_in[9];
    const float* ln2b = (const float*)d_in[10];
    const float* fc1w = (const float*)d_in[11];
    const float* fc1b = (const float*)d_in[12];
    const float* fc2w = (const float*)d_in[13];
    const float* fc2b = (const float*)d_in[14];
    const float* lnfg = (const float*)d_in[15];
    const float* lnfb = (const float*)d_in[16];
    const float* lmw  = (const float*)d_in[17];
    const float* lmb  = (const float*)d_in[18];

    char* ws = (char*)d_ws;
    float*          x    = (float*)(ws + 0);                  // 8.39 MB
    unsigned short* h    = (unsigned short*)(ws + 8388608);   // 4.19 MB
    unsigned short* qkv  = (unsigned short*)(ws + 12582912);  // 12.58 MB
    unsigned short* vt   = (unsigned short*)(ws + 25165824);  // 4.19 MB
    unsigned short* mid  = (unsigned short*)(ws + 29360128);  // 16.78 MB
    float*          nll  = (float*)(ws + 46137344);           // 8 KB
    float*          fc2p = (float*)(ws + 46145536);           // 16.78 MB
    unsigned short* lmwt = (unsigned short*)(ws + 62922752);  // 103.02 MB
    float*          pmax = fc2p;                              // reuse (free by lm)
    float*          psum = fc2p + (size_t)MROWS * NSTRIPS;
    const size_t UP_NEED = 442769408ull;
    bool upfront = (ws_size >= UP_NEED);
    unsigned short* qkvt = (unsigned short*)(ws + 165945344);
    unsigned short* fc1t, * fc2t;
    long qkvt_l, fc1t_l, fc2t_l;
    if (upfront) {
        fc1t = (unsigned short*)(ws + 241442816);
        fc2t = (unsigned short*)(ws + 342106112);
        qkvt_l = 3072 * 1024; fc1t_l = (long)FF * 1024; fc2t_l = (long)1024 * FF;
    } else {
        fc1t = (unsigned short*)(ws + 172236800);
        fc2t = (unsigned short*)(ws + 180625408);
        qkvt_l = 0; fc1t_l = 0; fc2t_l = 0;
    }
    float* logits = (float*)d_out;
    float* lossp  = logits + (size_t)MROWS * VOCAB;

    const long WQKV_L = (long)NHEAD * DMODEL * HSZ;
    if (upfront) {
        qkvpack64_kernel<<<dim3(16, 1, 48 * NLAYER), 256, 0, stream>>>(
            Wq, Wk, Wv, qkvt, WQKV_L, qkvt_l);
        wtranspose64_kernel<<<dim3(64, 16, NLAYER), 256, 0, stream>>>(
            fc1w, fc1t, DMODEL, FF, (long)DMODEL * FF, fc1t_l);
        wtranspose64_kernel<<<dim3(16, 64, NLAYER), 256, 0, stream>>>(
            fc2w, fc2t, FF, DMODEL, (long)FF * DMODEL, fc2t_l);
    }
    wtranspose64_kernel<<<dim3(786, 16, 1), 256, 0, stream>>>(
        lmw, lmwt, DMODEL, VOCAB, 0, 0);

    embed_ln_kernel<<<MROWS, 256, 0, stream>>>(idx, tok, pos, ln1g, ln1b, x, h);

    for (int l = 0; l < NLAYER; l++) {
        unsigned short* qkvt_p = qkvt + (size_t)l * qkvt_l;
        unsigned short* fc1t_p = fc1t + (size_t)l * fc1t_l;
        unsigned short* fc2t_p = fc2t + (size_t)l * fc2t_l;
        if (!upfront) {
            qkvpack64_kernel<<<dim3(16, 1, 48), 256, 0, stream>>>(
                Wq + (size_t)l * WQKV_L, Wk + (size_t)l * WQKV_L,
                Wv + (size_t)l * WQKV_L, qkvt, WQKV_L, 0);
            wtranspose64_kernel<<<dim3(64, 16, 1), 256, 0, stream>>>(
                fc1w + (size_t)l * DMODEL * FF, fc1t, DMODEL, FF, 0, 0);
            wtranspose64_kernel<<<dim3(16, 64, 1), 256, 0, stream>>>(
                fc2w + (size_t)l * FF * DMODEL, fc2t, FF, DMODEL, 0, 0);
        }
        gemm_qkv<<<dim3(16, 24), 512, 0, stream>>>(h, qkvt_p, qkv, vt);
        attn_fused_kernel<<<dim3(4, NHEAD, 8), 256, 0, stream>>>(qkv, vt, x);
        ln_kernel<<<MROWS, 256, 0, stream>>>(x, ln2g + l * DMODEL, ln2b + l * DMODEL, h);
        gemm_fc1<<<dim3(16, 32), 512, 0, stream>>>(h, fc1t_p, fc1b + (size_t)l * FF, mid);
        gemm_fc2<<<dim3(32, 8, 2), 256, 0, stream>>>(mid, fc2t_p, fc2p);
        const float* ng = (l < NLAYER - 1) ? ln1g + (l + 1) * DMODEL : lnfg;
        const float* nb = (l < NLAYER - 1) ? ln1b + (l + 1) * DMODEL : lnfb;
        fc2_merge_ln_kernel<<<MROWS, 256, 0, stream>>>(
            fc2p, fc2b + (size_t)l * DMODEL, ng, nb, x, h);
    }

    gemm_lm<<<dim3(8, 393), 512, 0, stream>>>(h, lmwt, lmb, logits, pmax, psum);

    loss_reduce_kernel<<<MROWS, 256, 0, stream>>>(pmax, psum, logits, tgt, nll);
    loss2_kernel<<<1, 256, 0, stream>>>(nll, lossp);
}